// Round 8
// baseline (284.787 us; speedup 1.0000x reference)
//
#include <hip/hip_runtime.h>
#include <hip/hip_bf16.h>
#include <math.h>

// N=500,000 nodes, E=16,000,000 edges, D_COEF=1, EPS=1e-12.
// Outputs (fp32, flat): v [N,2] then torque [N,1].
// torque = w0 * sum_sin / max(||sum||, eps)  (count cancels in normalize).
//
// R5: theta_q in entry -> 264 us BEST (phase1=145, phase2=119).
// R7/R11: gather FREE in phase 1, costly in phase 2. R8: LDS atomics
//     don't matter. R12: cursor padding null -> atomic theories dead.
// Issue-work arithmetic (R13): static work ~40-50 us/CU, measured 145.
//     2/3 of phase-1 time is unhidden latency at 9 waves/CU (LDS 45KB
//     -> 2-3 blocks/CU). R6/R10 never tested TLP cleanly (spill/scratch
//     artifacts). R13 = clean TLP test: K_BATCH 8192->4096, EPT 32->16,
//     LDS 24KB -> 6 blocks/CU (24 waves, 75%). Body = R12 verbatim.
//
// ws layout: uint cursor[256*CSTR] (16 KB), then uint bins[NB * CAP].

#define NBITS_Q   21
#define Q_MASK    ((1u << NBITS_Q) - 1)
#define Q_SCALE   131072.0f            // 2^21 / 16
#define Q_INV     (1.0f / 131072.0f)
#define BIN_SHIFT 11
#define BIN_W     2048
#define NB        245                  // ceil(500000/2048)
#define CAP       67584                // mean 65306 + ~9 sigma, mult of 4
#define K_BATCH   4096                 // edges per phase-1 block (R13: was 8192)
#define EPT       16                   // edges per thread, phase 1
#define CSTR      16                   // cursor stride: 1 counter / 64B line
#define SCALE_F   524288.0f            // 2^19 (phase-2 fixed-point)
#define INV_SCALE (1.0f / 524288.0f)
#define INV_2PI   0.15915494309189535f

typedef unsigned uint4_v __attribute__((ext_vector_type(4)));

__global__ void init_cursors(unsigned* __restrict__ cur, int cstride) {
    const int tid = threadIdx.x;
    for (int i = tid; i < 256 * CSTR; i += 256) cur[i] = 0u;
    __syncthreads();
    if (tid < NB) cur[tid * cstride] = (unsigned)tid * CAP;
}

__global__ __launch_bounds__(256) void bin_edges_sort(
        const float* __restrict__ theta,
        const int4* __restrict__ src4, const int4* __restrict__ dst4,
        unsigned* __restrict__ bins, unsigned* __restrict__ cursor,
        int E, int cstride)
{
    __shared__ unsigned      sorted[K_BATCH];   // 16 KB
    __shared__ unsigned char sbin[K_BATCH];     //  4 KB
    __shared__ unsigned      hist[256];
    __shared__ unsigned      base[256];
    __shared__ unsigned      gbase[256];
    __shared__ unsigned      lcnt[256];

    const int tid   = threadIdx.x;
    const int bb    = blockIdx.x;
    const int e0    = bb * K_BATCH;
    const int nval  = min(K_BATCH, E - e0);
    const int E4    = E >> 2;
    const int base4 = e0 >> 2;

    hist[tid] = 0u;
    lcnt[tid] = 0u;
    __syncthreads();

    // ---- A: load all src quads, then issue all theta gathers (MLP) ----
    int4 sQ[EPT / 4];
#pragma unroll
    for (int j = 0; j < EPT / 4; ++j) {
        const int idx4 = base4 + j * 256 + tid;
        sQ[j] = (idx4 < E4) ? src4[idx4] : make_int4(0, 0, 0, 0);
    }
    float tq[EPT];
#pragma unroll
    for (int j = 0; j < EPT / 4; ++j) {
        tq[j * 4 + 0] = theta[sQ[j].x];
        tq[j * 4 + 1] = theta[sQ[j].y];
        tq[j * 4 + 2] = theta[sQ[j].z];
        tq[j * 4 + 3] = theta[sQ[j].w];
    }

    // ---- B: load dst quads, build entries, histogram ----
    unsigned ent[EPT];
    unsigned bn[EPT];          // bin id, 0xFF = invalid
#pragma unroll
    for (int j = 0; j < EPT / 4; ++j) {
        const int idx4 = base4 + j * 256 + tid;
        const int q0   = j * 4;
        if (idx4 < E4) {
            const int4 d = dst4[idx4];
            const int dd[4] = {d.x, d.y, d.z, d.w};
#pragma unroll
            for (int k = 0; k < 4; ++k) {
                const unsigned b = (unsigned)dd[k] >> BIN_SHIFT;
                float qf = (tq[q0 + k] + 8.0f) * Q_SCALE + 0.5f;
                qf = fminf(fmaxf(qf, 0.0f), 2097151.0f);
                ent[q0 + k] = ((unsigned)(dd[k] & (BIN_W - 1)) << NBITS_Q)
                              | (unsigned)qf;
                bn[q0 + k]  = b;
                atomicAdd(&hist[b], 1u);
            }
        } else {
#pragma unroll
            for (int k = 0; k < 4; ++k) bn[q0 + k] = 0xFFu;
        }
    }
    __syncthreads();

    // ---- C: exclusive prefix scan of hist, single wave (lane owns 4 bins)
    if (tid < 64) {
        unsigned h[4];
#pragma unroll
        for (int k = 0; k < 4; ++k) h[k] = hist[tid * 4 + k];
        const unsigned tot = h[0] + h[1] + h[2] + h[3];
        unsigned s = tot;
#pragma unroll
        for (int off = 1; off < 64; off <<= 1) {
            const unsigned y = __shfl_up(s, off);
            if (tid >= off) s += y;
        }
        unsigned run = s - tot;              // exclusive across lanes
#pragma unroll
        for (int k = 0; k < 4; ++k) {
            base[tid * 4 + k] = run;
            run += h[k];
        }
#pragma unroll
        for (int k = 0; k < 4; ++k)
            if (h[k]) gbase[tid * 4 + k] =
                atomicAdd(&cursor[(tid * 4 + k) * cstride], h[k]);
    }
    __syncthreads();

    // ---- D: scatter into sorted LDS buffer ----
#pragma unroll
    for (int q = 0; q < EPT; ++q) {
        if (bn[q] != 0xFFu) {
            const unsigned b   = bn[q];
            const unsigned pos = base[b] + atomicAdd(&lcnt[b], 1u);
            sorted[pos] = ent[q];
            sbin[pos]   = (unsigned char)b;
        }
    }
    __syncthreads();

    // ---- E: coalesced write-out (contiguous run per bin) ----
    for (int l = tid; l < nval; l += 256) {
        const unsigned b    = sbin[l];
        const unsigned gpos = gbase[b] + ((unsigned)l - base[b]);
        if (gpos < (b + 1u) * CAP)          // ~9-sigma overflow guard
            bins[gpos] = sorted[l];
    }
}

__global__ __launch_bounds__(1024) void reduce_bins(
        const float* __restrict__ theta, const unsigned* __restrict__ bins,
        const unsigned* __restrict__ cursor, const float* __restrict__ v0p,
        const float* __restrict__ w0p, float* __restrict__ out,
        int N, int cstride)
{
    __shared__ float th[BIN_W];                         //  8 KB
    __shared__ unsigned long long acc[BIN_W];           // 16 KB
    const int b     = blockIdx.x;
    const int tid   = threadIdx.x;
    const int node0 = b * BIN_W;
    const int W     = min(BIN_W, N - node0);

    for (int j = tid; j < BIN_W; j += 1024) {
        th[j]  = (j < W) ? theta[node0 + j] : 0.f;
        acc[j] = 0ull;
    }
    __syncthreads();

    const unsigned  base  = (unsigned)b * CAP;
    const int       count = (int)(cursor[b * cstride] - base);
    const unsigned* bp    = bins + base;

    // stream 8 entries/thread/iter via two unit-stride nontemporal uint4 loads
    const int CH = 1024 * 8;
    int i0 = 0;
    for (; i0 + CH <= count; i0 += CH) {
        const uint4_v ea = __builtin_nontemporal_load(
            (const uint4_v*)(bp + i0 + tid * 4));
        const uint4_v eb = __builtin_nontemporal_load(
            (const uint4_v*)(bp + i0 + 4096 + tid * 4));
        const unsigned ee[8] = {ea.x, ea.y, ea.z, ea.w, eb.x, eb.y, eb.z, eb.w};
#pragma unroll
        for (int k = 0; k < 8; ++k) {
            const unsigned e = ee[k];
            const unsigned l = e >> NBITS_Q;
            const float ts = (float)(e & Q_MASK) * Q_INV - 8.0f;
            const float r  = (ts - th[l]) * INV_2PI;
            const float sn = __builtin_amdgcn_sinf(r);
            const float cs = __builtin_amdgcn_cosf(r);
            const unsigned cq = (unsigned)((cs + 1.0f) * SCALE_F + 0.5f);
            const unsigned sq = (unsigned)((sn + 1.0f) * SCALE_F + 0.5f);
            atomicAdd(&acc[l], (1ull << 56) | ((unsigned long long)cq << 28)
                               | (unsigned long long)sq);
        }
    }
    for (int i = i0 + tid; i < count; i += 1024) {
        const unsigned e = __builtin_nontemporal_load(bp + i);
        const unsigned l = e >> NBITS_Q;
        const float ts = (float)(e & Q_MASK) * Q_INV - 8.0f;
        const float r  = (ts - th[l]) * INV_2PI;
        const float sn = __builtin_amdgcn_sinf(r);
        const float cs = __builtin_amdgcn_cosf(r);
        const unsigned cq = (unsigned)((cs + 1.0f) * SCALE_F + 0.5f);
        const unsigned sq = (unsigned)((sn + 1.0f) * SCALE_F + 0.5f);
        atomicAdd(&acc[l], (1ull << 56) | ((unsigned long long)cq << 28)
                           | (unsigned long long)sq);
    }
    __syncthreads();

    // epilogue: unpack, v and torque (th[] is exact fp32 theta)
    const float v0 = *v0p, w0 = *w0p;
    for (int j = tid; j < W; j += 1024) {
        const float t  = th[j];
        const float rr = t * INV_2PI;
        const float sn = __builtin_amdgcn_sinf(rr);
        const float cs = __builtin_amdgcn_cosf(rr);
        ((float2*)out)[node0 + j] = make_float2(v0 * cs, v0 * sn);
        const unsigned long long P = acc[j];
        const float c  = (float)(unsigned)(P >> 56);
        const float xs = (float)(unsigned)((P >> 28) & 0xFFFFFFFull) * INV_SCALE - c;
        const float ys = (float)(unsigned)(P & 0xFFFFFFFull) * INV_SCALE - c;
        const float nrm = sqrtf(xs * xs + ys * ys);
        out[2 * N + node0 + j] = w0 * (ys / fmaxf(nrm, 1e-12f));
    }
}

// ---------- fallback path (round-2 kernels) if ws is too small ----------

__global__ void zero_ws_kernel(float4* __restrict__ ws, int n4) {
    int i = blockIdx.x * blockDim.x + threadIdx.x;
    if (i < n4) ws[i] = make_float4(0.f, 0.f, 0.f, 0.f);
}

__global__ void edge_kernel_fb(const float* __restrict__ theta,
                               const int4* __restrict__ src4,
                               const int4* __restrict__ dst4,
                               float2* __restrict__ acc, int E8) {
    int i = blockIdx.x * blockDim.x + threadIdx.x;
    if (i >= E8) return;
    const int4 s0 = src4[2 * i], s1 = src4[2 * i + 1];
    const int4 d0 = dst4[2 * i], d1 = dst4[2 * i + 1];
    const int ss[8] = {s0.x, s0.y, s0.z, s0.w, s1.x, s1.y, s1.z, s1.w};
    const int dd[8] = {d0.x, d0.y, d0.z, d0.w, d1.x, d1.y, d1.z, d1.w};
    float ts[8], td[8];
#pragma unroll
    for (int k = 0; k < 8; ++k) ts[k] = theta[ss[k]];
#pragma unroll
    for (int k = 0; k < 8; ++k) td[k] = theta[dd[k]];
#pragma unroll
    for (int k = 0; k < 8; ++k) {
        float sn, cs;
        __sincosf(ts[k] - td[k], &sn, &cs);
        atomicAdd(&acc[dd[k]].x, cs);
        atomicAdd(&acc[dd[k]].y, sn);
    }
}

__global__ void node_kernel_fb(const float* __restrict__ theta,
                               const float2* __restrict__ acc,
                               const float* __restrict__ v0p,
                               const float* __restrict__ w0p,
                               float* __restrict__ out, int N) {
    int i = blockIdx.x * blockDim.x + threadIdx.x;
    if (i >= N) return;
    const float v0 = *v0p, w0 = *w0p;
    float sn, cs;
    __sincosf(theta[i], &sn, &cs);
    ((float2*)out)[i] = make_float2(v0 * cs, v0 * sn);
    const float2 a = acc[i];
    const float nrm = sqrtf(a.x * a.x + a.y * a.y);
    out[2 * N + i] = w0 * (a.y / fmaxf(nrm, 1e-12f));
}

extern "C" void kernel_launch(void* const* d_in, const int* in_sizes, int n_in,
                              void* d_out, int out_size, void* d_ws, size_t ws_size,
                              hipStream_t stream) {
    const float* theta = (const float*)d_in[0];
    const int*   src   = (const int*)d_in[1];
    const int*   dst   = (const int*)d_in[2];
    const float* v0p   = (const float*)d_in[3];
    const float* w0p   = (const float*)d_in[4];
    float*       out   = (float*)d_out;

    const int N = in_sizes[0];   // 500,000
    const int E = in_sizes[1];   // 16,000,000

    const size_t bins_bytes = (size_t)NB * CAP * sizeof(unsigned);
    const size_t need_pad   = (size_t)256 * CSTR * 4 + bins_bytes;  // +16 KB
    const size_t need_min   = 1024 + bins_bytes;

    const int nblk  = (E + K_BATCH - 1) / K_BATCH;   // 3907
    const int nbins = (N + BIN_W - 1) / BIN_W;       // 245

    if (ws_size >= need_pad && N <= NB * BIN_W) {
        // tier 1: padded cursor (1 counter per 64B line)
        unsigned* cursor = (unsigned*)d_ws;
        unsigned* bins   = cursor + 256 * CSTR;

        init_cursors<<<1, 256, 0, stream>>>(cursor, CSTR);
        bin_edges_sort<<<nblk, 256, 0, stream>>>(theta, (const int4*)src,
                                                 (const int4*)dst,
                                                 bins, cursor, E, CSTR);
        reduce_bins<<<nbins, 1024, 0, stream>>>(theta, bins, cursor,
                                                v0p, w0p, out, N, CSTR);
    } else if (ws_size >= need_min && N <= NB * BIN_W) {
        // tier 2: packed cursor
        unsigned* cursor = (unsigned*)d_ws;
        unsigned* bins   = cursor + 256;

        init_cursors<<<1, 256, 0, stream>>>(cursor, 1);
        bin_edges_sort<<<nblk, 256, 0, stream>>>(theta, (const int4*)src,
                                                 (const int4*)dst,
                                                 bins, cursor, E, 1);
        reduce_bins<<<nbins, 1024, 0, stream>>>(theta, bins, cursor,
                                                v0p, w0p, out, N, 1);
    } else {
        float2* acc = (float2*)d_ws;
        {
            const int n4 = (2 * N) / 4;
            zero_ws_kernel<<<(n4 + 255) / 256, 256, 0, stream>>>((float4*)d_ws, n4);
        }
        {
            const int E8 = E / 8;
            edge_kernel_fb<<<(E8 + 255) / 256, 256, 0, stream>>>(
                theta, (const int4*)src, (const int4*)dst, acc, E8);
        }
        node_kernel_fb<<<(N + 255) / 256, 256, 0, stream>>>(theta, acc, v0p, w0p,
                                                            out, N);
    }
}